// Round 1
// baseline (363.520 us; speedup 1.0000x reference)
//
#include <hip/hip_runtime.h>

#define LOG2E 1.4426950408889634f

// ---------- bf16 helpers (raw ushort representation) ----------
__device__ __forceinline__ float b2f(unsigned short u) {
    unsigned int v = ((unsigned int)u) << 16;
    return __builtin_bit_cast(float, v);
}
__device__ __forceinline__ unsigned short f2b(float f) {
    unsigned int u = __builtin_bit_cast(unsigned int, f);
    u += 0x7fffu + ((u >> 16) & 1u);   // round-to-nearest-even
    return (unsigned short)(u >> 16);
}
__device__ __forceinline__ float fexp(float x) {           // e^x
    return __builtin_amdgcn_exp2f(x * LOG2E);
}
__device__ __forceinline__ float silu_f(float x) {
    return x * __builtin_amdgcn_rcpf(1.0f + fexp(-x));
}

// ---------- fp32 -> bf16 cast, 4 elems/thread ----------
__global__ __launch_bounds__(256) void cvt_bf16_k(const float* __restrict__ in,
                                                  unsigned short* __restrict__ out,
                                                  int n4) {
    int i = blockIdx.x * 256 + threadIdx.x;
    if (i >= n4) return;
    float4 v = ((const float4*)in)[i];
    *(ushort4*)(out + (size_t)i * 4) = make_ushort4(f2b(v.x), f2b(v.y), f2b(v.z), f2b(v.w));
}

// ---------- bf16 MFMA GEMM: C[M,N] = A[M,K] * B[N,K]^T ----------
// 128x128 block tile, BK=64, 4 waves in 2x2, each wave 64x64 via 4x4 of 16x16x32.
typedef __bf16 bf16x8 __attribute__((ext_vector_type(8)));
typedef float  fx4    __attribute__((ext_vector_type(4)));
typedef int    ix4    __attribute__((ext_vector_type(4)));
union FragU { ix4 i; bf16x8 b; };

template <bool OUT_BF16>
__global__ __launch_bounds__(256) void gemm_bt(const unsigned short* __restrict__ A,
                                               const unsigned short* __restrict__ B,
                                               void* __restrict__ C, int N, int K) {
    __shared__ __align__(16) unsigned short sA[128 * 64];
    __shared__ __align__(16) unsigned short sB[128 * 64];
    const int tid  = threadIdx.x;
    const int lane = tid & 63, wave = tid >> 6;
    const int bm = blockIdx.y * 128, bn = blockIdx.x * 128;
    const int wm = (wave >> 1) * 64, wn = (wave & 1) * 64;
    const int row16 = lane & 15, quad = lane >> 4;
    const int rs  = tid >> 3;          // staging row base (it*32 + rs)
    const int kc8 = (tid & 7) * 8;     // staging k offset (8 bf16 = 16B)
    fx4 acc[4][4] = {};

    for (int kt = 0; kt < K; kt += 64) {
#pragma unroll
        for (int it = 0; it < 4; ++it) {
            int r = it * 32 + rs;
            *(uint4*)(sA + r * 64 + kc8) = *(const uint4*)(A + (size_t)(bm + r) * K + kt + kc8);
            *(uint4*)(sB + r * 64 + kc8) = *(const uint4*)(B + (size_t)(bn + r) * K + kt + kc8);
        }
        __syncthreads();
#pragma unroll
        for (int kk = 0; kk < 64; kk += 32) {
            FragU af[4], bf[4];
#pragma unroll
            for (int t = 0; t < 4; ++t)
                af[t].i = *(const ix4*)(sA + (wm + t * 16 + row16) * 64 + kk + quad * 8);
#pragma unroll
            for (int t = 0; t < 4; ++t)
                bf[t].i = *(const ix4*)(sB + (wn + t * 16 + row16) * 64 + kk + quad * 8);
#pragma unroll
            for (int tm = 0; tm < 4; ++tm)
#pragma unroll
                for (int tn = 0; tn < 4; ++tn)
                    acc[tm][tn] = __builtin_amdgcn_mfma_f32_16x16x32_bf16(
                        af[tm].b, bf[tn].b, acc[tm][tn], 0, 0, 0);
        }
        __syncthreads();
    }
#pragma unroll
    for (int tm = 0; tm < 4; ++tm) {
        int row0 = bm + wm + tm * 16 + quad * 4;
#pragma unroll
        for (int tn = 0; tn < 4; ++tn) {
            int col = bn + wn + tn * 16 + row16;
#pragma unroll
            for (int r = 0; r < 4; ++r) {
                float v = acc[tm][tn][r];
                if (OUT_BF16)
                    ((unsigned short*)C)[(size_t)(row0 + r) * N + col] = f2b(v);
                else
                    ((float*)C)[(size_t)(row0 + r) * N + col] = v;
            }
        }
    }
}

// ---------- depthwise causal conv (K=4) + silu:  xc fp32 ----------
// block: 32 i-threads (8 ch each) x 8 m-threads; grid (8, 512)
__global__ __launch_bounds__(256) void conv_silu_k(const unsigned short* __restrict__ xz,
                                                   const float* __restrict__ cw,
                                                   float* __restrict__ xc) {
    const int ti = threadIdx.x & 31, tm = threadIdx.x >> 5;
    const int i0 = blockIdx.x * 256 + ti * 8;
    const int m  = blockIdx.y * 8 + tm;
    const int s  = m & 2047;
    float w[8][4];
    const float4* cw4 = (const float4*)cw;
#pragma unroll
    for (int j = 0; j < 8; ++j) {
        float4 t = cw4[i0 + j];
        w[j][0] = t.x; w[j][1] = t.y; w[j][2] = t.z; w[j][3] = t.w;
    }
    float acc[8] = {0, 0, 0, 0, 0, 0, 0, 0};
#pragma unroll
    for (int k = 0; k < 4; ++k) {
        int sr = s - 3 + k;
        if (sr >= 0) {
            const unsigned short* p = xz + (size_t)(m - 3 + k) * 4096 + i0;
            ushort4 a = *(const ushort4*)p;
            ushort4 b = *(const ushort4*)(p + 4);
            float v[8] = {b2f(a.x), b2f(a.y), b2f(a.z), b2f(a.w),
                          b2f(b.x), b2f(b.y), b2f(b.z), b2f(b.w)};
#pragma unroll
            for (int j = 0; j < 8; ++j) acc[j] += v[j] * w[j][k];
        }
    }
    float* q = xc + (size_t)m * 2048 + i0;
    *(float4*)q       = make_float4(silu_f(acc[0]), silu_f(acc[1]), silu_f(acc[2]), silu_f(acc[3]));
    *(float4*)(q + 4) = make_float4(silu_f(acc[4]), silu_f(acc[5]), silu_f(acc[6]), silu_f(acc[7]));
}

// ---------- xproj = xc @ W_x^T (N=33) fused with delta/G:  dg[m][17] ----------
// block: 32 rows x 8 k-groups; grid 128
__global__ __launch_bounds__(256) void xproj_k(const float* __restrict__ xc,
                                               const float* __restrict__ Wx,
                                               float* __restrict__ dg) {
    __shared__ float sW[33 * 256];
    __shared__ float red[32 * 33];
    const int tid = threadIdx.x;
    const int r = tid & 31, j = tid >> 5;
    const int m0 = blockIdx.x * 32;
    float acc[33];
#pragma unroll
    for (int p = 0; p < 33; ++p) acc[p] = 0.f;
    for (int kc = 0; kc < 8; ++kc) {
        __syncthreads();
#pragma unroll
        for (int p = 0; p < 33; ++p) sW[p * 256 + tid] = Wx[p * 2048 + kc * 256 + tid];
        __syncthreads();
        const float* xr = xc + (size_t)(m0 + r) * 2048 + kc * 256 + j * 32;
#pragma unroll
        for (int kk = 0; kk < 32; kk += 4) {
            float4 xv = *(const float4*)(xr + kk);
            float xs[4] = {xv.x, xv.y, xv.z, xv.w};
#pragma unroll
            for (int q = 0; q < 4; ++q) {
                const float* wp = sW + j * 32 + kk + q;
                float x = xs[q];
#pragma unroll
                for (int p = 0; p < 33; ++p) acc[p] += x * wp[p * 256];
            }
        }
    }
    __syncthreads();
#pragma unroll
    for (int p = 0; p < 33; ++p) sW[(r * 33 + p) * 8 + j] = acc[p];
    __syncthreads();
    for (int t = tid; t < 1056; t += 256) {
        float s = 0.f;
#pragma unroll
        for (int q = 0; q < 8; ++q) s += sW[t * 8 + q];
        red[t] = s;
    }
    __syncthreads();
    for (int t = tid; t < 544; t += 256) {
        int rr = t / 17, q = t - rr * 17;
        const float* v = red + rr * 33;
        float o;
        if (q == 0) {
            float xv = v[0];                       // softplus(delta_raw)
            o = (xv > 20.f) ? xv : log1pf(fexp(xv));
        } else {
            o = v[q] * v[q + 16];                  // G[n] = B[n]*C[n]
        }
        dg[(size_t)(m0 + rr) * 17 + q] = o;
    }
}

// ---------- SSM pointwise: y2 = (xc*(D + sum_n G*exp(delta*A))) * silu(z), bf16 ----------
// block covers 32 m x 64 i; grid (32, 128)
__global__ __launch_bounds__(256) void ssm_pw_k(const unsigned short* __restrict__ xz,
                                                const float* __restrict__ xc,
                                                const float* __restrict__ dg,
                                                const float* __restrict__ Alog,
                                                const float* __restrict__ Dv,
                                                unsigned short* __restrict__ y2) {
    __shared__ float sa[64 * 19];   // A2 = -exp(A_log)*log2e, stride 19 kills bank conflicts
    __shared__ float sdg[32 * 17];
    const int tid = threadIdx.x;
    const int bi = blockIdx.x, bm = blockIdx.y;
    for (int t = tid; t < 1024; t += 256) {
        float a = Alog[bi * 1024 + t];
        int il = t >> 4, n = t & 15;
        sa[il * 19 + n] = -fexp(a) * LOG2E;
    }
    for (int t = tid; t < 544; t += 256) sdg[t] = dg[(size_t)bm * 32 * 17 + t];
    __syncthreads();
    const int t_i = tid & 7, t_m = tid >> 3;
    const int m  = bm * 32 + t_m;
    const int i0 = bi * 64 + t_i * 8;
    const float delta = sdg[t_m * 17];
    float G[16];
#pragma unroll
    for (int n = 0; n < 16; ++n) G[n] = sdg[t_m * 17 + 1 + n];
    const float* xcp = xc + (size_t)m * 2048 + i0;
    float4 xv0 = *(const float4*)xcp, xv1 = *(const float4*)(xcp + 4);
    const unsigned short* zp = xz + (size_t)m * 4096 + 2048 + i0;
    ushort4 zu0 = *(const ushort4*)zp, zu1 = *(const ushort4*)(zp + 4);
    float4 d0 = *(const float4*)(Dv + i0), d1 = *(const float4*)(Dv + i0 + 4);
    float xcv[8] = {xv0.x, xv0.y, xv0.z, xv0.w, xv1.x, xv1.y, xv1.z, xv1.w};
    float zv[8]  = {b2f(zu0.x), b2f(zu0.y), b2f(zu0.z), b2f(zu0.w),
                    b2f(zu1.x), b2f(zu1.y), b2f(zu1.z), b2f(zu1.w)};
    float dv[8]  = {d0.x, d0.y, d0.z, d0.w, d1.x, d1.y, d1.z, d1.w};
    unsigned short outv[8];
#pragma unroll
    for (int ii = 0; ii < 8; ++ii) {
        const float* ap = sa + (t_i * 8 + ii) * 19;
        float ssum = 0.f;
#pragma unroll
        for (int n = 0; n < 16; ++n)
            ssum += G[n] * __builtin_amdgcn_exp2f(delta * ap[n]);
        float y = xcv[ii] * (dv[ii] + ssum);
        outv[ii] = f2b(y * silu_f(zv[ii]));
    }
    unsigned short* q = y2 + (size_t)m * 2048 + i0;
    *(ushort4*)q       = make_ushort4(outv[0], outv[1], outv[2], outv[3]);
    *(ushort4*)(q + 4) = make_ushort4(outv[4], outv[5], outv[6], outv[7]);
}

// ---------- launch ----------
extern "C" void kernel_launch(void* const* d_in, const int* in_sizes, int n_in,
                              void* d_out, int out_size, void* d_ws, size_t ws_size,
                              hipStream_t stream) {
    const float* x      = (const float*)d_in[0];   // (2,2048,1024)
    const float* W_in   = (const float*)d_in[1];   // (4096,1024)
    const float* conv_w = (const float*)d_in[2];   // (2048,1,4)
    const float* W_x    = (const float*)d_in[3];   // (33,2048)
    const float* A_log  = (const float*)d_in[4];   // (2048,16)
    const float* Dvec   = (const float*)d_in[5];   // (2048,)
    const float* W_out  = (const float*)d_in[6];   // (1024,2048)

    char* ws = (char*)d_ws;
    unsigned short* xb  = (unsigned short*)(ws);              //  8,388,608  x bf16
    unsigned short* wib = (unsigned short*)(ws + 8388608);    //  8,388,608  W_in bf16
    unsigned short* wob = (unsigned short*)(ws + 16777216);   //  4,194,304  W_out bf16
    unsigned short* xz  = (unsigned short*)(ws + 20971520);   // 33,554,432  xz bf16 (4096x4096)
    float*          xcf = (float*)        (ws + 54525952);    // 33,554,432  xc fp32 (4096x2048)
    float*          dgp = (float*)        (ws + 88080384);    //    278,528  delta+G (4096x17)
    unsigned short* y2  = (unsigned short*)(ws + 88358912);   // 16,777,216  y2 bf16 (4096x2048)

    cvt_bf16_k<<<4096, 256, 0, stream>>>(x, xb, 1048576);
    cvt_bf16_k<<<4096, 256, 0, stream>>>(W_in, wib, 1048576);
    cvt_bf16_k<<<2048, 256, 0, stream>>>(W_out, wob, 524288);
    // xz[m,i] = sum_h x[m,h] * W_in[i,h]
    gemm_bt<true><<<dim3(32, 32), 256, 0, stream>>>(xb, wib, xz, 4096, 1024);
    conv_silu_k<<<dim3(8, 512), 256, 0, stream>>>(xz, conv_w, xcf);
    xproj_k<<<128, 256, 0, stream>>>(xcf, W_x, dgp);
    ssm_pw_k<<<dim3(32, 128), 256, 0, stream>>>(xz, xcf, dgp, A_log, Dvec, y2);
    // out[m,h] = sum_i y2[m,i] * W_out[h,i]
    gemm_bt<false><<<dim3(8, 32), 256, 0, stream>>>(y2, wob, (float*)d_out, 1024, 2048);
}

// Round 2
// 269.786 us; speedup vs baseline: 1.3474x; 1.3474x over previous
//
#include <hip/hip_runtime.h>

#define LOG2E 1.4426950408889634f

// ---------- bf16 helpers (raw ushort representation) ----------
__device__ __forceinline__ float b2f(unsigned short u) {
    unsigned int v = ((unsigned int)u) << 16;
    return __builtin_bit_cast(float, v);
}
__device__ __forceinline__ unsigned short f2b(float f) {
    unsigned int u = __builtin_bit_cast(unsigned int, f);
    u += 0x7fffu + ((u >> 16) & 1u);   // round-to-nearest-even
    return (unsigned short)(u >> 16);
}
__device__ __forceinline__ float fexp(float x) {           // e^x
    return __builtin_amdgcn_exp2f(x * LOG2E);
}
__device__ __forceinline__ float silu_f(float x) {
    return x * __builtin_amdgcn_rcpf(1.0f + fexp(-x));
}

// ---------- fp32 -> bf16 cast, 4 elems/thread ----------
__global__ __launch_bounds__(256) void cvt_bf16_k(const float* __restrict__ in,
                                                  unsigned short* __restrict__ out,
                                                  int n4) {
    int i = blockIdx.x * 256 + threadIdx.x;
    if (i >= n4) return;
    float4 v = ((const float4*)in)[i];
    *(ushort4*)(out + (size_t)i * 4) = make_ushort4(f2b(v.x), f2b(v.y), f2b(v.z), f2b(v.w));
}

// ---------- bf16 MFMA GEMM: C[M,N] = A[M,K] * B[N,K]^T ----------
// 128x128 block tile, BK=64, 4 waves in 2x2, each wave 64x64 via 4x4 of 16x16x32.
typedef __bf16 bf16x8 __attribute__((ext_vector_type(8)));
typedef float  fx4    __attribute__((ext_vector_type(4)));
typedef int    ix4    __attribute__((ext_vector_type(4)));
union FragU { ix4 i; bf16x8 b; };

template <bool OUT_BF16>
__global__ __launch_bounds__(256) void gemm_bt(const unsigned short* __restrict__ A,
                                               const unsigned short* __restrict__ B,
                                               void* __restrict__ C, int N, int K) {
    __shared__ __align__(16) unsigned short sA[128 * 64];
    __shared__ __align__(16) unsigned short sB[128 * 64];
    const int tid  = threadIdx.x;
    const int lane = tid & 63, wave = tid >> 6;
    const int bm = blockIdx.y * 128, bn = blockIdx.x * 128;
    const int wm = (wave >> 1) * 64, wn = (wave & 1) * 64;
    const int row16 = lane & 15, quad = lane >> 4;
    const int rs  = tid >> 3;          // staging row base (it*32 + rs)
    const int kc8 = (tid & 7) * 8;     // staging k offset (8 bf16 = 16B)
    fx4 acc[4][4] = {};

    for (int kt = 0; kt < K; kt += 64) {
#pragma unroll
        for (int it = 0; it < 4; ++it) {
            int r = it * 32 + rs;
            *(uint4*)(sA + r * 64 + kc8) = *(const uint4*)(A + (size_t)(bm + r) * K + kt + kc8);
            *(uint4*)(sB + r * 64 + kc8) = *(const uint4*)(B + (size_t)(bn + r) * K + kt + kc8);
        }
        __syncthreads();
#pragma unroll
        for (int kk = 0; kk < 64; kk += 32) {
            FragU af[4], bf[4];
#pragma unroll
            for (int t = 0; t < 4; ++t)
                af[t].i = *(const ix4*)(sA + (wm + t * 16 + row16) * 64 + kk + quad * 8);
#pragma unroll
            for (int t = 0; t < 4; ++t)
                bf[t].i = *(const ix4*)(sB + (wn + t * 16 + row16) * 64 + kk + quad * 8);
#pragma unroll
            for (int tm = 0; tm < 4; ++tm)
#pragma unroll
                for (int tn = 0; tn < 4; ++tn)
                    acc[tm][tn] = __builtin_amdgcn_mfma_f32_16x16x32_bf16(
                        af[tm].b, bf[tn].b, acc[tm][tn], 0, 0, 0);
        }
        __syncthreads();
    }
#pragma unroll
    for (int tm = 0; tm < 4; ++tm) {
        int row0 = bm + wm + tm * 16 + quad * 4;
#pragma unroll
        for (int tn = 0; tn < 4; ++tn) {
            int col = bn + wn + tn * 16 + row16;
#pragma unroll
            for (int r = 0; r < 4; ++r) {
                float v = acc[tm][tn][r];
                if (OUT_BF16)
                    ((unsigned short*)C)[(size_t)(row0 + r) * N + col] = f2b(v);
                else
                    ((float*)C)[(size_t)(row0 + r) * N + col] = v;
            }
        }
    }
}

// ---------- depthwise causal conv (K=4) + silu:  xc fp32 + bf16 ----------
// block: 32 i-threads (8 ch each) x 8 m-threads; grid (8, 512)
__global__ __launch_bounds__(256) void conv_silu_k(const unsigned short* __restrict__ xz,
                                                   const float* __restrict__ cw,
                                                   float* __restrict__ xc,
                                                   unsigned short* __restrict__ xcb) {
    const int ti = threadIdx.x & 31, tm = threadIdx.x >> 5;
    const int i0 = blockIdx.x * 256 + ti * 8;
    const int m  = blockIdx.y * 8 + tm;
    const int s  = m & 2047;
    float w[8][4];
    const float4* cw4 = (const float4*)cw;
#pragma unroll
    for (int j = 0; j < 8; ++j) {
        float4 t = cw4[i0 + j];
        w[j][0] = t.x; w[j][1] = t.y; w[j][2] = t.z; w[j][3] = t.w;
    }
    float acc[8] = {0, 0, 0, 0, 0, 0, 0, 0};
#pragma unroll
    for (int k = 0; k < 4; ++k) {
        int sr = s - 3 + k;
        if (sr >= 0) {
            const unsigned short* p = xz + (size_t)(m - 3 + k) * 4096 + i0;
            ushort4 a = *(const ushort4*)p;
            ushort4 b = *(const ushort4*)(p + 4);
            float v[8] = {b2f(a.x), b2f(a.y), b2f(a.z), b2f(a.w),
                          b2f(b.x), b2f(b.y), b2f(b.z), b2f(b.w)};
#pragma unroll
            for (int j = 0; j < 8; ++j) acc[j] += v[j] * w[j][k];
        }
    }
    float o[8];
#pragma unroll
    for (int j = 0; j < 8; ++j) o[j] = silu_f(acc[j]);
    float* q = xc + (size_t)m * 2048 + i0;
    *(float4*)q       = make_float4(o[0], o[1], o[2], o[3]);
    *(float4*)(q + 4) = make_float4(o[4], o[5], o[6], o[7]);
    unsigned short* qb = xcb + (size_t)m * 2048 + i0;
    *(ushort4*)qb       = make_ushort4(f2b(o[0]), f2b(o[1]), f2b(o[2]), f2b(o[3]));
    *(ushort4*)(qb + 4) = make_ushort4(f2b(o[4]), f2b(o[5]), f2b(o[6]), f2b(o[7]));
}

// ---------- xproj via MFMA: dg[m][17] from xc_b @ Wx_b^T (N=33 padded to 48) ----------
// grid 256 blocks x 256 thr. Block = one 16-row M-tile; wave w takes K-quarter.
// No main-loop LDS: A frags straight from global (16x64B segs), B is L2-hot 132 KB.
__global__ __launch_bounds__(256) void xproj_mfma(const unsigned short* __restrict__ xcb,
                                                  const unsigned short* __restrict__ wxb,
                                                  float* __restrict__ dg) {
    __shared__ float sX[4][16][49];
    const int tid = threadIdx.x;
    const int lane = tid & 63, wave = tid >> 6;
    const int row16 = lane & 15, quad = lane >> 4;
    const int m0 = blockIdx.x * 16;
    fx4 acc[3] = {};
    const unsigned short* ap = xcb + (size_t)(m0 + row16) * 2048 + wave * 512 + quad * 8;
    const unsigned short* bp = wxb + (size_t)row16 * 2048 + wave * 512 + quad * 8;
#pragma unroll 4
    for (int kk = 0; kk < 512; kk += 32) {
        FragU a, b0, b1, b2;
        a.i  = *(const ix4*)(ap + kk);
        b0.i = *(const ix4*)(bp + kk);
        b1.i = *(const ix4*)(bp + 16 * 2048 + kk);
        b2.i = *(const ix4*)(bp + 32 * 2048 + kk);
        acc[0] = __builtin_amdgcn_mfma_f32_16x16x32_bf16(a.b, b0.b, acc[0], 0, 0, 0);
        acc[1] = __builtin_amdgcn_mfma_f32_16x16x32_bf16(a.b, b1.b, acc[1], 0, 0, 0);
        acc[2] = __builtin_amdgcn_mfma_f32_16x16x32_bf16(a.b, b2.b, acc[2], 0, 0, 0);
    }
    // partial tile -> LDS: m_local = quad*4+r, n = t*16+row16 (cols>=33 are junk, ignored)
#pragma unroll
    for (int t = 0; t < 3; ++t)
#pragma unroll
        for (int r = 0; r < 4; ++r)
            sX[wave][quad * 4 + r][t * 16 + row16] = acc[t][r];
    __syncthreads();
    for (int idx = tid; idx < 272; idx += 256) {
        int rr = idx / 17, q = idx - rr * 17;
        float o;
        if (q == 0) {
            float v = sX[0][rr][0] + sX[1][rr][0] + sX[2][rr][0] + sX[3][rr][0];
            o = (v > 20.f) ? v : log1pf(fexp(v));          // softplus(delta_raw)
        } else {
            float bs = sX[0][rr][q]      + sX[1][rr][q]      + sX[2][rr][q]      + sX[3][rr][q];
            float cs = sX[0][rr][q + 16] + sX[1][rr][q + 16] + sX[2][rr][q + 16] + sX[3][rr][q + 16];
            o = bs * cs;                                   // G[n] = B[n]*C[n]
        }
        dg[(size_t)(m0 + rr) * 17 + q] = o;
    }
}

// ---------- SSM pointwise: y2 = (xc*(D + sum_n G*exp(delta*A))) * silu(z), bf16 ----------
// block covers 32 m x 64 i; grid (32, 128)
__global__ __launch_bounds__(256) void ssm_pw_k(const unsigned short* __restrict__ xz,
                                                const float* __restrict__ xc,
                                                const float* __restrict__ dg,
                                                const float* __restrict__ Alog,
                                                const float* __restrict__ Dv,
                                                unsigned short* __restrict__ y2) {
    __shared__ float sa[64 * 19];   // A2 = -exp(A_log)*log2e, stride 19 kills bank conflicts
    __shared__ float sdg[32 * 17];
    const int tid = threadIdx.x;
    const int bi = blockIdx.x, bm = blockIdx.y;
    for (int t = tid; t < 1024; t += 256) {
        float a = Alog[bi * 1024 + t];
        int il = t >> 4, n = t & 15;
        sa[il * 19 + n] = -fexp(a) * LOG2E;
    }
    for (int t = tid; t < 544; t += 256) sdg[t] = dg[(size_t)bm * 32 * 17 + t];
    __syncthreads();
    const int t_i = tid & 7, t_m = tid >> 3;
    const int m  = bm * 32 + t_m;
    const int i0 = bi * 64 + t_i * 8;
    const float delta = sdg[t_m * 17];
    float G[16];
#pragma unroll
    for (int n = 0; n < 16; ++n) G[n] = sdg[t_m * 17 + 1 + n];
    const float* xcp = xc + (size_t)m * 2048 + i0;
    float4 xv0 = *(const float4*)xcp, xv1 = *(const float4*)(xcp + 4);
    const unsigned short* zp = xz + (size_t)m * 4096 + 2048 + i0;
    ushort4 zu0 = *(const ushort4*)zp, zu1 = *(const ushort4*)(zp + 4);
    float4 d0 = *(const float4*)(Dv + i0), d1 = *(const float4*)(Dv + i0 + 4);
    float xcv[8] = {xv0.x, xv0.y, xv0.z, xv0.w, xv1.x, xv1.y, xv1.z, xv1.w};
    float zv[8]  = {b2f(zu0.x), b2f(zu0.y), b2f(zu0.z), b2f(zu0.w),
                    b2f(zu1.x), b2f(zu1.y), b2f(zu1.z), b2f(zu1.w)};
    float dv[8]  = {d0.x, d0.y, d0.z, d0.w, d1.x, d1.y, d1.z, d1.w};
    unsigned short outv[8];
#pragma unroll
    for (int ii = 0; ii < 8; ++ii) {
        const float* ap = sa + (t_i * 8 + ii) * 19;
        float ssum = 0.f;
#pragma unroll
        for (int n = 0; n < 16; ++n)
            ssum += G[n] * __builtin_amdgcn_exp2f(delta * ap[n]);
        float y = xcv[ii] * (dv[ii] + ssum);
        outv[ii] = f2b(y * silu_f(zv[ii]));
    }
    unsigned short* q = y2 + (size_t)m * 2048 + i0;
    *(ushort4*)q       = make_ushort4(outv[0], outv[1], outv[2], outv[3]);
    *(ushort4*)(q + 4) = make_ushort4(outv[4], outv[5], outv[6], outv[7]);
}

// ---------- launch ----------
extern "C" void kernel_launch(void* const* d_in, const int* in_sizes, int n_in,
                              void* d_out, int out_size, void* d_ws, size_t ws_size,
                              hipStream_t stream) {
    const float* x      = (const float*)d_in[0];   // (2,2048,1024)
    const float* W_in   = (const float*)d_in[1];   // (4096,1024)
    const float* conv_w = (const float*)d_in[2];   // (2048,1,4)
    const float* W_x    = (const float*)d_in[3];   // (33,2048)
    const float* A_log  = (const float*)d_in[4];   // (2048,16)
    const float* Dvec   = (const float*)d_in[5];   // (2048,)
    const float* W_out  = (const float*)d_in[6];   // (1024,2048)

    char* ws = (char*)d_ws;
    unsigned short* xb  = (unsigned short*)(ws);              //  8,388,608  x bf16
    unsigned short* wib = (unsigned short*)(ws + 8388608);    //  8,388,608  W_in bf16
    unsigned short* wob = (unsigned short*)(ws + 16777216);   //  4,194,304  W_out bf16
    unsigned short* xz  = (unsigned short*)(ws + 20971520);   // 33,554,432  xz bf16 (4096x4096)
    float*          xcf = (float*)        (ws + 54525952);    // 33,554,432  xc fp32 (4096x2048)
    float*          dgp = (float*)        (ws + 88080384);    //    278,528  delta+G (4096x17)
    unsigned short* y2  = (unsigned short*)(ws + 88358912);   // 16,777,216  y2 bf16 (4096x2048)
    unsigned short* xcb = (unsigned short*)(ws + 105136128);  // 16,777,216  xc bf16 (4096x2048)
    unsigned short* wxb = (unsigned short*)(ws + 121913344);  //    196,608  Wx bf16 (48x2048 padded)

    cvt_bf16_k<<<4096, 256, 0, stream>>>(x, xb, 1048576);
    cvt_bf16_k<<<4096, 256, 0, stream>>>(W_in, wib, 1048576);
    cvt_bf16_k<<<2048, 256, 0, stream>>>(W_out, wob, 524288);
    cvt_bf16_k<<<66, 256, 0, stream>>>(W_x, wxb, 16896);      // rows 33..47 left junk, never used
    // xz[m,i] = sum_h x[m,h] * W_in[i,h]
    gemm_bt<true><<<dim3(32, 32), 256, 0, stream>>>(xb, wib, xz, 4096, 1024);
    conv_silu_k<<<dim3(8, 512), 256, 0, stream>>>(xz, conv_w, xcf, xcb);
    xproj_mfma<<<256, 256, 0, stream>>>(xcb, wxb, dgp);
    ssm_pw_k<<<dim3(32, 128), 256, 0, stream>>>(xz, xcf, dgp, A_log, Dvec, y2);
    // out[m,h] = sum_i y2[m,i] * W_out[h,i]
    gemm_bt<false><<<dim3(8, 32), 256, 0, stream>>>(y2, wob, (float*)d_out, 1024, 2048);
}

// Round 3
// 251.522 us; speedup vs baseline: 1.4453x; 1.0726x over previous
//
#include <hip/hip_runtime.h>

#define LOG2E 1.4426950408889634f

// ---------- bf16 helpers (raw ushort representation) ----------
__device__ __forceinline__ float b2f(unsigned short u) {
    unsigned int v = ((unsigned int)u) << 16;
    return __builtin_bit_cast(float, v);
}
__device__ __forceinline__ unsigned short f2b(float f) {
    unsigned int u = __builtin_bit_cast(unsigned int, f);
    u += 0x7fffu + ((u >> 16) & 1u);   // round-to-nearest-even
    return (unsigned short)(u >> 16);
}
__device__ __forceinline__ float fexp(float x) {           // e^x
    return __builtin_amdgcn_exp2f(x * LOG2E);
}
__device__ __forceinline__ float silu_f(float x) {
    return x * __builtin_amdgcn_rcpf(1.0f + fexp(-x));
}

// async global->LDS 16B per lane; lptr must be wave-uniform (dest = base + lane*16)
typedef const __attribute__((address_space(1))) unsigned int* gas_t;
typedef __attribute__((address_space(3))) unsigned int* las_t;
__device__ __forceinline__ void gl2lds16(const unsigned short* g, unsigned short* l) {
    __builtin_amdgcn_global_load_lds((gas_t)(const void*)g, (las_t)(void*)l, 16, 0, 0);
}

// ---------- fp32 -> bf16 cast, 4 elems/thread ----------
__global__ __launch_bounds__(256) void cvt_bf16_k(const float* __restrict__ in,
                                                  unsigned short* __restrict__ out,
                                                  int n4) {
    int i = blockIdx.x * 256 + threadIdx.x;
    if (i >= n4) return;
    float4 v = ((const float4*)in)[i];
    *(ushort4*)(out + (size_t)i * 4) = make_ushort4(f2b(v.x), f2b(v.y), f2b(v.z), f2b(v.w));
}

// ---------- bf16 MFMA GEMM: C[M,N] = A[M,K] * B[N,K]^T ----------
// 128x128 block tile, BK=64, 4 waves 2x2, each wave 64x64 via 4x4 of 16x16x32.
// Staging: global_load_lds width=16 (ladder step 3), XOR-swizzled 16B columns
// (phys c16 = logical c16 ^ (row&7)) to kill ds_read_b128 bank conflicts.
typedef __bf16 bf16x8 __attribute__((ext_vector_type(8)));
typedef float  fx4    __attribute__((ext_vector_type(4)));
typedef int    ix4    __attribute__((ext_vector_type(4)));
union FragU { ix4 i; bf16x8 b; };

template <bool OUT_BF16>
__global__ __launch_bounds__(256) void gemm_bt(const unsigned short* __restrict__ A,
                                               const unsigned short* __restrict__ B,
                                               void* __restrict__ C, int N, int K) {
    __shared__ __align__(16) unsigned short sA[128 * 64];
    __shared__ __align__(16) unsigned short sB[128 * 64];
    const int tid  = threadIdx.x;
    const int lane = tid & 63, wave = tid >> 6;
    const int bm = blockIdx.y * 128, bn = blockIdx.x * 128;
    const int wm = (wave >> 1) * 64, wn = (wave & 1) * 64;
    const int row16 = lane & 15, quad = lane >> 4;
    // staging: chunk c = wave*4+it covers rows c*8..c*8+7; lane covers
    // row c*8 + (lane>>3), swizzled 16B col (lane&7)^(lane>>3)
    const int srow = lane >> 3;
    const int sc16 = (lane & 7) ^ srow;
    const unsigned short* gA = A + (size_t)(bm + wave * 32 + srow) * K + sc16 * 8;
    const unsigned short* gB = B + (size_t)(bn + wave * 32 + srow) * K + sc16 * 8;
    unsigned short* lA = sA + (wave * 4) * 512;   // wave-uniform
    unsigned short* lB = sB + (wave * 4) * 512;
    fx4 acc[4][4] = {};

    for (int kt = 0; kt < K; kt += 64) {
#pragma unroll
        for (int it = 0; it < 4; ++it) {
            gl2lds16(gA + (size_t)it * 8 * K + kt, lA + it * 512);
            gl2lds16(gB + (size_t)it * 8 * K + kt, lB + it * 512);
        }
        __syncthreads();
#pragma unroll
        for (int kk = 0; kk < 64; kk += 32) {
            FragU af[4], bf[4];
#pragma unroll
            for (int t = 0; t < 4; ++t) {
                int ra = wm + t * 16 + row16;
                af[t].i = *(const ix4*)(sA + ra * 64 + ((quad + (kk >> 3)) ^ (ra & 7)) * 8);
            }
#pragma unroll
            for (int t = 0; t < 4; ++t) {
                int rb = wn + t * 16 + row16;
                bf[t].i = *(const ix4*)(sB + rb * 64 + ((quad + (kk >> 3)) ^ (rb & 7)) * 8);
            }
#pragma unroll
            for (int tm = 0; tm < 4; ++tm)
#pragma unroll
                for (int tn = 0; tn < 4; ++tn)
                    acc[tm][tn] = __builtin_amdgcn_mfma_f32_16x16x32_bf16(
                        af[tm].b, bf[tn].b, acc[tm][tn], 0, 0, 0);
        }
        __syncthreads();
    }
#pragma unroll
    for (int tm = 0; tm < 4; ++tm) {
        int row0 = bm + wm + tm * 16 + quad * 4;
#pragma unroll
        for (int tn = 0; tn < 4; ++tn) {
            int col = bn + wn + tn * 16 + row16;
#pragma unroll
            for (int r = 0; r < 4; ++r) {
                float v = acc[tm][tn][r];
                if (OUT_BF16)
                    ((unsigned short*)C)[(size_t)(row0 + r) * N + col] = f2b(v);
                else
                    ((float*)C)[(size_t)(row0 + r) * N + col] = v;
            }
        }
    }
}

// ---------- depthwise causal conv (K=4) + silu:  xc fp32 + bf16 ----------
// block: 32 i-threads (8 ch each) x 8 m-threads; grid (8, 512)
__global__ __launch_bounds__(256) void conv_silu_k(const unsigned short* __restrict__ xz,
                                                   const float* __restrict__ cw,
                                                   float* __restrict__ xc,
                                                   unsigned short* __restrict__ xcb) {
    const int ti = threadIdx.x & 31, tm = threadIdx.x >> 5;
    const int i0 = blockIdx.x * 256 + ti * 8;
    const int m  = blockIdx.y * 8 + tm;
    const int s  = m & 2047;
    float w[8][4];
    const float4* cw4 = (const float4*)cw;
#pragma unroll
    for (int j = 0; j < 8; ++j) {
        float4 t = cw4[i0 + j];
        w[j][0] = t.x; w[j][1] = t.y; w[j][2] = t.z; w[j][3] = t.w;
    }
    float acc[8] = {0, 0, 0, 0, 0, 0, 0, 0};
#pragma unroll
    for (int k = 0; k < 4; ++k) {
        int sr = s - 3 + k;
        if (sr >= 0) {
            const unsigned short* p = xz + (size_t)(m - 3 + k) * 4096 + i0;
            ushort4 a = *(const ushort4*)p;
            ushort4 b = *(const ushort4*)(p + 4);
            float v[8] = {b2f(a.x), b2f(a.y), b2f(a.z), b2f(a.w),
                          b2f(b.x), b2f(b.y), b2f(b.z), b2f(b.w)};
#pragma unroll
            for (int j = 0; j < 8; ++j) acc[j] += v[j] * w[j][k];
        }
    }
    float o[8];
#pragma unroll
    for (int j = 0; j < 8; ++j) o[j] = silu_f(acc[j]);
    float* q = xc + (size_t)m * 2048 + i0;
    *(float4*)q       = make_float4(o[0], o[1], o[2], o[3]);
    *(float4*)(q + 4) = make_float4(o[4], o[5], o[6], o[7]);
    unsigned short* qb = xcb + (size_t)m * 2048 + i0;
    *(ushort4*)qb       = make_ushort4(f2b(o[0]), f2b(o[1]), f2b(o[2]), f2b(o[3]));
    *(ushort4*)(qb + 4) = make_ushort4(f2b(o[4]), f2b(o[5]), f2b(o[6]), f2b(o[7]));
}

// ---------- xproj via MFMA: dg[m][17] from xc_b @ Wx_b^T (N=33 padded to 48) ----------
__global__ __launch_bounds__(256) void xproj_mfma(const unsigned short* __restrict__ xcb,
                                                  const unsigned short* __restrict__ wxb,
                                                  float* __restrict__ dg) {
    __shared__ float sX[4][16][49];
    const int tid = threadIdx.x;
    const int lane = tid & 63, wave = tid >> 6;
    const int row16 = lane & 15, quad = lane >> 4;
    const int m0 = blockIdx.x * 16;
    fx4 acc[3] = {};
    const unsigned short* ap = xcb + (size_t)(m0 + row16) * 2048 + wave * 512 + quad * 8;
    const unsigned short* bp = wxb + (size_t)row16 * 2048 + wave * 512 + quad * 8;
#pragma unroll 4
    for (int kk = 0; kk < 512; kk += 32) {
        FragU a, b0, b1, b2;
        a.i  = *(const ix4*)(ap + kk);
        b0.i = *(const ix4*)(bp + kk);
        b1.i = *(const ix4*)(bp + 16 * 2048 + kk);
        b2.i = *(const ix4*)(bp + 32 * 2048 + kk);
        acc[0] = __builtin_amdgcn_mfma_f32_16x16x32_bf16(a.b, b0.b, acc[0], 0, 0, 0);
        acc[1] = __builtin_amdgcn_mfma_f32_16x16x32_bf16(a.b, b1.b, acc[1], 0, 0, 0);
        acc[2] = __builtin_amdgcn_mfma_f32_16x16x32_bf16(a.b, b2.b, acc[2], 0, 0, 0);
    }
#pragma unroll
    for (int t = 0; t < 3; ++t)
#pragma unroll
        for (int r = 0; r < 4; ++r)
            sX[wave][quad * 4 + r][t * 16 + row16] = acc[t][r];
    __syncthreads();
    for (int idx = tid; idx < 272; idx += 256) {
        int rr = idx / 17, q = idx - rr * 17;
        float o;
        if (q == 0) {
            float v = sX[0][rr][0] + sX[1][rr][0] + sX[2][rr][0] + sX[3][rr][0];
            o = (v > 20.f) ? v : log1pf(fexp(v));          // softplus(delta_raw)
        } else {
            float bs = sX[0][rr][q]      + sX[1][rr][q]      + sX[2][rr][q]      + sX[3][rr][q];
            float cs = sX[0][rr][q + 16] + sX[1][rr][q + 16] + sX[2][rr][q + 16] + sX[3][rr][q + 16];
            o = bs * cs;                                   // G[n] = B[n]*C[n]
        }
        dg[(size_t)(m0 + rr) * 17 + q] = o;
    }
}

// ---------- SSM pointwise: y2 = (xc*(D + sum_n G*exp(delta*A))) * silu(z), bf16 ----------
__global__ __launch_bounds__(256) void ssm_pw_k(const unsigned short* __restrict__ xz,
                                                const float* __restrict__ xc,
                                                const float* __restrict__ dg,
                                                const float* __restrict__ Alog,
                                                const float* __restrict__ Dv,
                                                unsigned short* __restrict__ y2) {
    __shared__ float sa[64 * 19];
    __shared__ float sdg[32 * 17];
    const int tid = threadIdx.x;
    const int bi = blockIdx.x, bm = blockIdx.y;
    for (int t = tid; t < 1024; t += 256) {
        float a = Alog[bi * 1024 + t];
        int il = t >> 4, n = t & 15;
        sa[il * 19 + n] = -fexp(a) * LOG2E;
    }
    for (int t = tid; t < 544; t += 256) sdg[t] = dg[(size_t)bm * 32 * 17 + t];
    __syncthreads();
    const int t_i = tid & 7, t_m = tid >> 3;
    const int m  = bm * 32 + t_m;
    const int i0 = bi * 64 + t_i * 8;
    const float delta = sdg[t_m * 17];
    float G[16];
#pragma unroll
    for (int n = 0; n < 16; ++n) G[n] = sdg[t_m * 17 + 1 + n];
    const float* xcp = xc + (size_t)m * 2048 + i0;
    float4 xv0 = *(const float4*)xcp, xv1 = *(const float4*)(xcp + 4);
    const unsigned short* zp = xz + (size_t)m * 4096 + 2048 + i0;
    ushort4 zu0 = *(const ushort4*)zp, zu1 = *(const ushort4*)(zp + 4);
    float4 d0 = *(const float4*)(Dv + i0), d1 = *(const float4*)(Dv + i0 + 4);
    float xcv[8] = {xv0.x, xv0.y, xv0.z, xv0.w, xv1.x, xv1.y, xv1.z, xv1.w};
    float zv[8]  = {b2f(zu0.x), b2f(zu0.y), b2f(zu0.z), b2f(zu0.w),
                    b2f(zu1.x), b2f(zu1.y), b2f(zu1.z), b2f(zu1.w)};
    float dv[8]  = {d0.x, d0.y, d0.z, d0.w, d1.x, d1.y, d1.z, d1.w};
    unsigned short outv[8];
#pragma unroll
    for (int ii = 0; ii < 8; ++ii) {
        const float* ap = sa + (t_i * 8 + ii) * 19;
        float ssum = 0.f;
#pragma unroll
        for (int n = 0; n < 16; ++n)
            ssum += G[n] * __builtin_amdgcn_exp2f(delta * ap[n]);
        float y = xcv[ii] * (dv[ii] + ssum);
        outv[ii] = f2b(y * silu_f(zv[ii]));
    }
    unsigned short* q = y2 + (size_t)m * 2048 + i0;
    *(ushort4*)q       = make_ushort4(outv[0], outv[1], outv[2], outv[3]);
    *(ushort4*)(q + 4) = make_ushort4(outv[4], outv[5], outv[6], outv[7]);
}

// ---------- launch ----------
extern "C" void kernel_launch(void* const* d_in, const int* in_sizes, int n_in,
                              void* d_out, int out_size, void* d_ws, size_t ws_size,
                              hipStream_t stream) {
    const float* x      = (const float*)d_in[0];   // (2,2048,1024)
    const float* W_in   = (const float*)d_in[1];   // (4096,1024)
    const float* conv_w = (const float*)d_in[2];   // (2048,1,4)
    const float* W_x    = (const float*)d_in[3];   // (33,2048)
    const float* A_log  = (const float*)d_in[4];   // (2048,16)
    const float* Dvec   = (const float*)d_in[5];   // (2048,)
    const float* W_out  = (const float*)d_in[6];   // (1024,2048)

    char* ws = (char*)d_ws;
    unsigned short* xb  = (unsigned short*)(ws);              //  8,388,608  x bf16
    unsigned short* wib = (unsigned short*)(ws + 8388608);    //  8,388,608  W_in bf16
    unsigned short* wob = (unsigned short*)(ws + 16777216);   //  4,194,304  W_out bf16
    unsigned short* xz  = (unsigned short*)(ws + 20971520);   // 33,554,432  xz bf16 (4096x4096)
    float*          xcf = (float*)        (ws + 54525952);    // 33,554,432  xc fp32 (4096x2048)
    float*          dgp = (float*)        (ws + 88080384);    //    278,528  delta+G (4096x17)
    unsigned short* y2  = (unsigned short*)(ws + 88358912);   // 16,777,216  y2 bf16 (4096x2048)
    unsigned short* xcb = (unsigned short*)(ws + 105136128);  // 16,777,216  xc bf16 (4096x2048)
    unsigned short* wxb = (unsigned short*)(ws + 121913344);  //    196,608  Wx bf16 (48x2048 padded)

    cvt_bf16_k<<<4096, 256, 0, stream>>>(x, xb, 1048576);
    cvt_bf16_k<<<4096, 256, 0, stream>>>(W_in, wib, 1048576);
    cvt_bf16_k<<<2048, 256, 0, stream>>>(W_out, wob, 524288);
    cvt_bf16_k<<<66, 256, 0, stream>>>(W_x, wxb, 16896);      // rows 33..47 junk, never read
    // xz[m,i] = sum_h x[m,h] * W_in[i,h]
    gemm_bt<true><<<dim3(32, 32), 256, 0, stream>>>(xb, wib, xz, 4096, 1024);
    conv_silu_k<<<dim3(8, 512), 256, 0, stream>>>(xz, conv_w, xcf, xcb);
    xproj_mfma<<<256, 256, 0, stream>>>(xcb, wxb, dgp);
    ssm_pw_k<<<dim3(32, 128), 256, 0, stream>>>(xz, xcf, dgp, A_log, Dvec, y2);
    // out[m,h] = sum_i y2[m,i] * W_out[h,i]
    gemm_bt<false><<<dim3(8, 32), 256, 0, stream>>>(y2, wob, (float*)d_out, 1024, 2048);
}

// Round 4
// 233.125 us; speedup vs baseline: 1.5593x; 1.0789x over previous
//
#include <hip/hip_runtime.h>

#define LOG2E 1.4426950408889634f

// ---------- bf16 helpers (raw ushort representation) ----------
__device__ __forceinline__ float b2f(unsigned short u) {
    unsigned int v = ((unsigned int)u) << 16;
    return __builtin_bit_cast(float, v);
}
__device__ __forceinline__ unsigned short f2b(float f) {
    unsigned int u = __builtin_bit_cast(unsigned int, f);
    u += 0x7fffu + ((u >> 16) & 1u);   // round-to-nearest-even
    return (unsigned short)(u >> 16);
}
__device__ __forceinline__ float fexp(float x) {           // e^x
    return __builtin_amdgcn_exp2f(x * LOG2E);
}
__device__ __forceinline__ float silu_f(float x) {
    return x * __builtin_amdgcn_rcpf(1.0f + fexp(-x));
}

// async global->LDS 16B per lane; lptr must be wave-uniform (dest = base + lane*16)
typedef const __attribute__((address_space(1))) unsigned int* gas_t;
typedef __attribute__((address_space(3))) unsigned int* las_t;
__device__ __forceinline__ void gl2lds16(const unsigned short* g, unsigned short* l) {
    __builtin_amdgcn_global_load_lds((gas_t)(const void*)g, (las_t)(void*)l, 16, 0, 0);
}

// ---------- fused fp32 -> bf16 cast for all 4 arrays, one launch ----------
// grid = 4096 (x) + 4096 (W_in) + 2048 (W_out) + 66 (W_x) = 10306 blocks, all exact fits
__global__ __launch_bounds__(256) void cvt_all_k(const float* __restrict__ x,
                                                 const float* __restrict__ W_in,
                                                 const float* __restrict__ W_out,
                                                 const float* __restrict__ W_x,
                                                 unsigned short* __restrict__ xb,
                                                 unsigned short* __restrict__ wib,
                                                 unsigned short* __restrict__ wob,
                                                 unsigned short* __restrict__ wxb) {
    int b = blockIdx.x;
    const float* src;
    unsigned short* dst;
    if (b < 4096)       { src = x;     dst = xb;  }
    else if (b < 8192)  { src = W_in;  dst = wib; b -= 4096; }
    else if (b < 10240) { src = W_out; dst = wob; b -= 8192; }
    else                { src = W_x;   dst = wxb; b -= 10240; }
    int i = b * 256 + threadIdx.x;
    float4 v = ((const float4*)src)[i];
    *(ushort4*)(dst + (size_t)i * 4) = make_ushort4(f2b(v.x), f2b(v.y), f2b(v.z), f2b(v.w));
}

// ---------- bf16 MFMA GEMM: C[M,N] = A[M,K] * B[N,K]^T ----------
// 128x128 block tile, BK=64, 4 waves 2x2, each wave 64x64 via 4x4 of 16x16x32.
// Staging: global_load_lds width=16, XOR-swizzled 16B columns (phys c16 =
// logical c16 ^ (row&7)) -> ds_read_b128 bank conflicts = 0 (verified R3).
typedef __bf16 bf16x8 __attribute__((ext_vector_type(8)));
typedef float  fx4    __attribute__((ext_vector_type(4)));
typedef int    ix4    __attribute__((ext_vector_type(4)));
union FragU { ix4 i; bf16x8 b; };

template <bool OUT_BF16>
__global__ __launch_bounds__(256) void gemm_bt(const unsigned short* __restrict__ A,
                                               const unsigned short* __restrict__ B,
                                               void* __restrict__ C, int N, int K) {
    __shared__ __align__(16) unsigned short sA[128 * 64];
    __shared__ __align__(16) unsigned short sB[128 * 64];
    const int tid  = threadIdx.x;
    const int lane = tid & 63, wave = tid >> 6;
    const int bm = blockIdx.y * 128, bn = blockIdx.x * 128;
    const int wm = (wave >> 1) * 64, wn = (wave & 1) * 64;
    const int row16 = lane & 15, quad = lane >> 4;
    const int srow = lane >> 3;
    const int sc16 = (lane & 7) ^ srow;
    const unsigned short* gA = A + (size_t)(bm + wave * 32 + srow) * K + sc16 * 8;
    const unsigned short* gB = B + (size_t)(bn + wave * 32 + srow) * K + sc16 * 8;
    unsigned short* lA = sA + (wave * 4) * 512;   // wave-uniform
    unsigned short* lB = sB + (wave * 4) * 512;
    fx4 acc[4][4] = {};

    for (int kt = 0; kt < K; kt += 64) {
#pragma unroll
        for (int it = 0; it < 4; ++it) {
            gl2lds16(gA + (size_t)it * 8 * K + kt, lA + it * 512);
            gl2lds16(gB + (size_t)it * 8 * K + kt, lB + it * 512);
        }
        __syncthreads();
#pragma unroll
        for (int kk = 0; kk < 64; kk += 32) {
            FragU af[4], bf[4];
#pragma unroll
            for (int t = 0; t < 4; ++t) {
                int ra = wm + t * 16 + row16;
                af[t].i = *(const ix4*)(sA + ra * 64 + ((quad + (kk >> 3)) ^ (ra & 7)) * 8);
            }
#pragma unroll
            for (int t = 0; t < 4; ++t) {
                int rb = wn + t * 16 + row16;
                bf[t].i = *(const ix4*)(sB + rb * 64 + ((quad + (kk >> 3)) ^ (rb & 7)) * 8);
            }
#pragma unroll
            for (int tm = 0; tm < 4; ++tm)
#pragma unroll
                for (int tn = 0; tn < 4; ++tn)
                    acc[tm][tn] = __builtin_amdgcn_mfma_f32_16x16x32_bf16(
                        af[tm].b, bf[tn].b, acc[tm][tn], 0, 0, 0);
        }
        __syncthreads();
    }
#pragma unroll
    for (int tm = 0; tm < 4; ++tm) {
        int row0 = bm + wm + tm * 16 + quad * 4;
#pragma unroll
        for (int tn = 0; tn < 4; ++tn) {
            int col = bn + wn + tn * 16 + row16;
#pragma unroll
            for (int r = 0; r < 4; ++r) {
                float v = acc[tm][tn][r];
                if (OUT_BF16)
                    ((unsigned short*)C)[(size_t)(row0 + r) * N + col] = f2b(v);
                else
                    ((float*)C)[(size_t)(row0 + r) * N + col] = v;
            }
        }
    }
}

// ---------- narrow GEMM for C[M,1024]: 128x64 tile, 512 blocks = 2/CU ----------
// 4 waves stacked in M (wave tile 32x64 = 2x4 frags); same swizzled staging.
__global__ __launch_bounds__(256) void gemm_bt_n64(const unsigned short* __restrict__ A,
                                                   const unsigned short* __restrict__ B,
                                                   float* __restrict__ C, int N, int K) {
    __shared__ __align__(16) unsigned short sA[128 * 64];
    __shared__ __align__(16) unsigned short sB[64 * 64];
    const int tid  = threadIdx.x;
    const int lane = tid & 63, wave = tid >> 6;
    const int bm = blockIdx.y * 128, bn = blockIdx.x * 64;
    const int wm = wave * 32;
    const int row16 = lane & 15, quad = lane >> 4;
    const int srow = lane >> 3;
    const int sc16 = (lane & 7) ^ srow;
    const unsigned short* gA = A + (size_t)(bm + wave * 32 + srow) * K + sc16 * 8;
    const unsigned short* gB = B + (size_t)(bn + wave * 16 + srow) * K + sc16 * 8;
    unsigned short* lA = sA + (wave * 4) * 512;   // 4 A-chunks / wave
    unsigned short* lB = sB + (wave * 2) * 512;   // 2 B-chunks / wave
    fx4 acc[2][4] = {};

    for (int kt = 0; kt < K; kt += 64) {
#pragma unroll
        for (int it = 0; it < 4; ++it)
            gl2lds16(gA + (size_t)it * 8 * K + kt, lA + it * 512);
#pragma unroll
        for (int it = 0; it < 2; ++it)
            gl2lds16(gB + (size_t)it * 8 * K + kt, lB + it * 512);
        __syncthreads();
#pragma unroll
        for (int kk = 0; kk < 64; kk += 32) {
            FragU af[2], bf[4];
#pragma unroll
            for (int t = 0; t < 2; ++t) {
                int ra = wm + t * 16 + row16;
                af[t].i = *(const ix4*)(sA + ra * 64 + ((quad + (kk >> 3)) ^ (ra & 7)) * 8);
            }
#pragma unroll
            for (int t = 0; t < 4; ++t) {
                int rb = t * 16 + row16;
                bf[t].i = *(const ix4*)(sB + rb * 64 + ((quad + (kk >> 3)) ^ (rb & 7)) * 8);
            }
#pragma unroll
            for (int tm = 0; tm < 2; ++tm)
#pragma unroll
                for (int tn = 0; tn < 4; ++tn)
                    acc[tm][tn] = __builtin_amdgcn_mfma_f32_16x16x32_bf16(
                        af[tm].b, bf[tn].b, acc[tm][tn], 0, 0, 0);
        }
        __syncthreads();
    }
#pragma unroll
    for (int tm = 0; tm < 2; ++tm) {
        int row0 = bm + wm + tm * 16 + quad * 4;
#pragma unroll
        for (int tn = 0; tn < 4; ++tn) {
            int col = bn + tn * 16 + row16;
#pragma unroll
            for (int r = 0; r < 4; ++r)
                C[(size_t)(row0 + r) * N + col] = acc[tm][tn][r];
        }
    }
}

// ---------- depthwise causal conv (K=4) + silu -> xc bf16 only ----------
// block: 32 i-threads (8 ch each) x 8 m-threads; grid (8, 512)
__global__ __launch_bounds__(256) void conv_silu_k(const unsigned short* __restrict__ xz,
                                                   const float* __restrict__ cw,
                                                   unsigned short* __restrict__ xcb) {
    const int ti = threadIdx.x & 31, tm = threadIdx.x >> 5;
    const int i0 = blockIdx.x * 256 + ti * 8;
    const int m  = blockIdx.y * 8 + tm;
    const int s  = m & 2047;
    float w[8][4];
    const float4* cw4 = (const float4*)cw;
#pragma unroll
    for (int j = 0; j < 8; ++j) {
        float4 t = cw4[i0 + j];
        w[j][0] = t.x; w[j][1] = t.y; w[j][2] = t.z; w[j][3] = t.w;
    }
    float acc[8] = {0, 0, 0, 0, 0, 0, 0, 0};
#pragma unroll
    for (int k = 0; k < 4; ++k) {
        int sr = s - 3 + k;
        if (sr >= 0) {
            const unsigned short* p = xz + (size_t)(m - 3 + k) * 4096 + i0;
            ushort4 a = *(const ushort4*)p;
            ushort4 b = *(const ushort4*)(p + 4);
            float v[8] = {b2f(a.x), b2f(a.y), b2f(a.z), b2f(a.w),
                          b2f(b.x), b2f(b.y), b2f(b.z), b2f(b.w)};
#pragma unroll
            for (int j = 0; j < 8; ++j) acc[j] += v[j] * w[j][k];
        }
    }
    unsigned short* qb = xcb + (size_t)m * 2048 + i0;
    *(ushort4*)qb       = make_ushort4(f2b(silu_f(acc[0])), f2b(silu_f(acc[1])),
                                       f2b(silu_f(acc[2])), f2b(silu_f(acc[3])));
    *(ushort4*)(qb + 4) = make_ushort4(f2b(silu_f(acc[4])), f2b(silu_f(acc[5])),
                                       f2b(silu_f(acc[6])), f2b(silu_f(acc[7])));
}

// ---------- xproj via MFMA: dg[m][17] from xc_b @ Wx_b^T (N=33 padded to 48) ----------
__global__ __launch_bounds__(256) void xproj_mfma(const unsigned short* __restrict__ xcb,
                                                  const unsigned short* __restrict__ wxb,
                                                  float* __restrict__ dg) {
    __shared__ float sX[4][16][49];
    const int tid = threadIdx.x;
    const int lane = tid & 63, wave = tid >> 6;
    const int row16 = lane & 15, quad = lane >> 4;
    const int m0 = blockIdx.x * 16;
    fx4 acc[3] = {};
    const unsigned short* ap = xcb + (size_t)(m0 + row16) * 2048 + wave * 512 + quad * 8;
    const unsigned short* bp = wxb + (size_t)row16 * 2048 + wave * 512 + quad * 8;
#pragma unroll 4
    for (int kk = 0; kk < 512; kk += 32) {
        FragU a, b0, b1, b2;
        a.i  = *(const ix4*)(ap + kk);
        b0.i = *(const ix4*)(bp + kk);
        b1.i = *(const ix4*)(bp + 16 * 2048 + kk);
        b2.i = *(const ix4*)(bp + 32 * 2048 + kk);
        acc[0] = __builtin_amdgcn_mfma_f32_16x16x32_bf16(a.b, b0.b, acc[0], 0, 0, 0);
        acc[1] = __builtin_amdgcn_mfma_f32_16x16x32_bf16(a.b, b1.b, acc[1], 0, 0, 0);
        acc[2] = __builtin_amdgcn_mfma_f32_16x16x32_bf16(a.b, b2.b, acc[2], 0, 0, 0);
    }
#pragma unroll
    for (int t = 0; t < 3; ++t)
#pragma unroll
        for (int r = 0; r < 4; ++r)
            sX[wave][quad * 4 + r][t * 16 + row16] = acc[t][r];
    __syncthreads();
    for (int idx = tid; idx < 272; idx += 256) {
        int rr = idx / 17, q = idx - rr * 17;
        float o;
        if (q == 0) {
            float v = sX[0][rr][0] + sX[1][rr][0] + sX[2][rr][0] + sX[3][rr][0];
            o = (v > 20.f) ? v : log1pf(fexp(v));          // softplus(delta_raw)
        } else {
            float bs = sX[0][rr][q]      + sX[1][rr][q]      + sX[2][rr][q]      + sX[3][rr][q];
            float cs = sX[0][rr][q + 16] + sX[1][rr][q + 16] + sX[2][rr][q + 16] + sX[3][rr][q + 16];
            o = bs * cs;                                   // G[n] = B[n]*C[n]
        }
        dg[(size_t)(m0 + rr) * 17 + q] = o;
    }
}

// ---------- SSM pointwise: y2 = (xc*(D + sum_n G*exp(delta*A))) * silu(z), bf16 ----------
__global__ __launch_bounds__(256) void ssm_pw_k(const unsigned short* __restrict__ xz,
                                                const unsigned short* __restrict__ xcb,
                                                const float* __restrict__ dg,
                                                const float* __restrict__ Alog,
                                                const float* __restrict__ Dv,
                                                unsigned short* __restrict__ y2) {
    __shared__ float sa[64 * 19];
    __shared__ float sdg[32 * 17];
    const int tid = threadIdx.x;
    const int bi = blockIdx.x, bm = blockIdx.y;
    for (int t = tid; t < 1024; t += 256) {
        float a = Alog[bi * 1024 + t];
        int il = t >> 4, n = t & 15;
        sa[il * 19 + n] = -fexp(a) * LOG2E;
    }
    for (int t = tid; t < 544; t += 256) sdg[t] = dg[(size_t)bm * 32 * 17 + t];
    __syncthreads();
    const int t_i = tid & 7, t_m = tid >> 3;
    const int m  = bm * 32 + t_m;
    const int i0 = bi * 64 + t_i * 8;
    const float delta = sdg[t_m * 17];
    float G[16];
#pragma unroll
    for (int n = 0; n < 16; ++n) G[n] = sdg[t_m * 17 + 1 + n];
    const unsigned short* xcp = xcb + (size_t)m * 2048 + i0;
    ushort4 xu0 = *(const ushort4*)xcp, xu1 = *(const ushort4*)(xcp + 4);
    const unsigned short* zp = xz + (size_t)m * 4096 + 2048 + i0;
    ushort4 zu0 = *(const ushort4*)zp, zu1 = *(const ushort4*)(zp + 4);
    float4 d0 = *(const float4*)(Dv + i0), d1 = *(const float4*)(Dv + i0 + 4);
    float xcv[8] = {b2f(xu0.x), b2f(xu0.y), b2f(xu0.z), b2f(xu0.w),
                    b2f(xu1.x), b2f(xu1.y), b2f(xu1.z), b2f(xu1.w)};
    float zv[8]  = {b2f(zu0.x), b2f(zu0.y), b2f(zu0.z), b2f(zu0.w),
                    b2f(zu1.x), b2f(zu1.y), b2f(zu1.z), b2f(zu1.w)};
    float dv[8]  = {d0.x, d0.y, d0.z, d0.w, d1.x, d1.y, d1.z, d1.w};
    unsigned short outv[8];
#pragma unroll
    for (int ii = 0; ii < 8; ++ii) {
        const float* ap = sa + (t_i * 8 + ii) * 19;
        float ssum = 0.f;
#pragma unroll
        for (int n = 0; n < 16; ++n)
            ssum += G[n] * __builtin_amdgcn_exp2f(delta * ap[n]);
        float y = xcv[ii] * (dv[ii] + ssum);
        outv[ii] = f2b(y * silu_f(zv[ii]));
    }
    unsigned short* q = y2 + (size_t)m * 2048 + i0;
    *(ushort4*)q       = make_ushort4(outv[0], outv[1], outv[2], outv[3]);
    *(ushort4*)(q + 4) = make_ushort4(outv[4], outv[5], outv[6], outv[7]);
}

// ---------- launch ----------
extern "C" void kernel_launch(void* const* d_in, const int* in_sizes, int n_in,
                              void* d_out, int out_size, void* d_ws, size_t ws_size,
                              hipStream_t stream) {
    const float* x      = (const float*)d_in[0];   // (2,2048,1024)
    const float* W_in   = (const float*)d_in[1];   // (4096,1024)
    const float* conv_w = (const float*)d_in[2];   // (2048,1,4)
    const float* W_x    = (const float*)d_in[3];   // (33,2048)
    const float* A_log  = (const float*)d_in[4];   // (2048,16)
    const float* Dvec   = (const float*)d_in[5];   // (2048,)
    const float* W_out  = (const float*)d_in[6];   // (1024,2048)

    char* ws = (char*)d_ws;
    unsigned short* xb  = (unsigned short*)(ws);              //  8,388,608  x bf16
    unsigned short* wib = (unsigned short*)(ws + 8388608);    //  8,388,608  W_in bf16
    unsigned short* wob = (unsigned short*)(ws + 16777216);   //  4,194,304  W_out bf16
    unsigned short* xz  = (unsigned short*)(ws + 20971520);   // 33,554,432  xz bf16 (4096x4096)
    float*          dgp = (float*)        (ws + 54525952);    //    278,528  delta+G (4096x17)
    unsigned short* y2  = (unsigned short*)(ws + 54804480);   // 16,777,216  y2 bf16 (4096x2048)
    unsigned short* xcb = (unsigned short*)(ws + 71581696);   // 16,777,216  xc bf16 (4096x2048)
    unsigned short* wxb = (unsigned short*)(ws + 88358912);   //    196,608  Wx bf16 (48x2048 padded)

    cvt_all_k<<<10306, 256, 0, stream>>>(x, W_in, W_out, W_x, xb, wib, wob, wxb);
    // xz[m,i] = sum_h x[m,h] * W_in[i,h]
    gemm_bt<true><<<dim3(32, 32), 256, 0, stream>>>(xb, wib, xz, 4096, 1024);
    conv_silu_k<<<dim3(8, 512), 256, 0, stream>>>(xz, conv_w, xcb);
    xproj_mfma<<<256, 256, 0, stream>>>(xcb, wxb, dgp);
    ssm_pw_k<<<dim3(32, 128), 256, 0, stream>>>(xz, xcb, dgp, A_log, Dvec, y2);
    // out[m,h] = sum_i y2[m,i] * W_out[h,i]
    gemm_bt_n64<<<dim3(16, 32), 256, 0, stream>>>(y2, wob, (float*)d_out, 1024, 2048);
}

// Round 5
// 217.895 us; speedup vs baseline: 1.6683x; 1.0699x over previous
//
#include <hip/hip_runtime.h>

#define LOG2E 1.4426950408889634f

// ---------- bf16 helpers (raw ushort representation) ----------
__device__ __forceinline__ float b2f(unsigned short u) {
    unsigned int v = ((unsigned int)u) << 16;
    return __builtin_bit_cast(float, v);
}
__device__ __forceinline__ unsigned short f2b(float f) {
    unsigned int u = __builtin_bit_cast(unsigned int, f);
    u += 0x7fffu + ((u >> 16) & 1u);   // round-to-nearest-even
    return (unsigned short)(u >> 16);
}
__device__ __forceinline__ float fexp(float x) {           // e^x
    return __builtin_amdgcn_exp2f(x * LOG2E);
}
__device__ __forceinline__ float silu_f(float x) {
    return x * __builtin_amdgcn_rcpf(1.0f + fexp(-x));
}

// async global->LDS 16B per lane; lptr must be wave-uniform (dest = base + lane*16)
typedef const __attribute__((address_space(1))) unsigned int* gas_t;
typedef __attribute__((address_space(3))) unsigned int* las_t;
__device__ __forceinline__ void gl2lds16(const unsigned short* g, unsigned short* l) {
    __builtin_amdgcn_global_load_lds((gas_t)(const void*)g, (las_t)(void*)l, 16, 0, 0);
}

// ---------- fused fp32 -> bf16 cast for all 4 arrays, one launch ----------
__global__ __launch_bounds__(256) void cvt_all_k(const float* __restrict__ x,
                                                 const float* __restrict__ W_in,
                                                 const float* __restrict__ W_out,
                                                 const float* __restrict__ W_x,
                                                 unsigned short* __restrict__ xb,
                                                 unsigned short* __restrict__ wib,
                                                 unsigned short* __restrict__ wob,
                                                 unsigned short* __restrict__ wxb) {
    int b = blockIdx.x;
    const float* src;
    unsigned short* dst;
    if (b < 4096)       { src = x;     dst = xb;  }
    else if (b < 8192)  { src = W_in;  dst = wib; b -= 4096; }
    else if (b < 10240) { src = W_out; dst = wob; b -= 8192; }
    else                { src = W_x;   dst = wxb; b -= 10240; }
    int i = b * 256 + threadIdx.x;
    float4 v = ((const float4*)src)[i];
    *(ushort4*)(dst + (size_t)i * 4) = make_ushort4(f2b(v.x), f2b(v.y), f2b(v.z), f2b(v.w));
}

// ---------- bf16 MFMA GEMM: C[M,N] = A[M,K] * B[N,K]^T ----------
// 128x128 tile, BK=64, global_load_lds w=16, XOR-swizzled (conflicts=0, verified R3).
typedef __bf16 bf16x8 __attribute__((ext_vector_type(8)));
typedef float  fx4    __attribute__((ext_vector_type(4)));
typedef int    ix4    __attribute__((ext_vector_type(4)));
union FragU { ix4 i; bf16x8 b; };

template <bool OUT_BF16>
__global__ __launch_bounds__(256) void gemm_bt(const unsigned short* __restrict__ A,
                                               const unsigned short* __restrict__ B,
                                               void* __restrict__ C, int N, int K) {
    __shared__ __align__(16) unsigned short sA[128 * 64];
    __shared__ __align__(16) unsigned short sB[128 * 64];
    const int tid  = threadIdx.x;
    const int lane = tid & 63, wave = tid >> 6;
    const int bm = blockIdx.y * 128, bn = blockIdx.x * 128;
    const int wm = (wave >> 1) * 64, wn = (wave & 1) * 64;
    const int row16 = lane & 15, quad = lane >> 4;
    const int srow = lane >> 3;
    const int sc16 = (lane & 7) ^ srow;
    const unsigned short* gA = A + (size_t)(bm + wave * 32 + srow) * K + sc16 * 8;
    const unsigned short* gB = B + (size_t)(bn + wave * 32 + srow) * K + sc16 * 8;
    unsigned short* lA = sA + (wave * 4) * 512;   // wave-uniform
    unsigned short* lB = sB + (wave * 4) * 512;
    fx4 acc[4][4] = {};

    for (int kt = 0; kt < K; kt += 64) {
#pragma unroll
        for (int it = 0; it < 4; ++it) {
            gl2lds16(gA + (size_t)it * 8 * K + kt, lA + it * 512);
            gl2lds16(gB + (size_t)it * 8 * K + kt, lB + it * 512);
        }
        __syncthreads();
#pragma unroll
        for (int kk = 0; kk < 64; kk += 32) {
            FragU af[4], bf[4];
#pragma unroll
            for (int t = 0; t < 4; ++t) {
                int ra = wm + t * 16 + row16;
                af[t].i = *(const ix4*)(sA + ra * 64 + ((quad + (kk >> 3)) ^ (ra & 7)) * 8);
            }
#pragma unroll
            for (int t = 0; t < 4; ++t) {
                int rb = wn + t * 16 + row16;
                bf[t].i = *(const ix4*)(sB + rb * 64 + ((quad + (kk >> 3)) ^ (rb & 7)) * 8);
            }
#pragma unroll
            for (int tm = 0; tm < 4; ++tm)
#pragma unroll
                for (int tn = 0; tn < 4; ++tn)
                    acc[tm][tn] = __builtin_amdgcn_mfma_f32_16x16x32_bf16(
                        af[tm].b, bf[tn].b, acc[tm][tn], 0, 0, 0);
        }
        __syncthreads();
    }
#pragma unroll
    for (int tm = 0; tm < 4; ++tm) {
        int row0 = bm + wm + tm * 16 + quad * 4;
#pragma unroll
        for (int tn = 0; tn < 4; ++tn) {
            int col = bn + wn + tn * 16 + row16;
#pragma unroll
            for (int r = 0; r < 4; ++r) {
                float v = acc[tm][tn][r];
                if (OUT_BF16)
                    ((unsigned short*)C)[(size_t)(row0 + r) * N + col] = f2b(v);
                else
                    ((float*)C)[(size_t)(row0 + r) * N + col] = v;
            }
        }
    }
}

// ---------- narrow GEMM for C[M,1024]: 128x64 tile, 512 blocks = 2/CU ----------
__global__ __launch_bounds__(256) void gemm_bt_n64(const unsigned short* __restrict__ A,
                                                   const unsigned short* __restrict__ B,
                                                   float* __restrict__ C, int N, int K) {
    __shared__ __align__(16) unsigned short sA[128 * 64];
    __shared__ __align__(16) unsigned short sB[64 * 64];
    const int tid  = threadIdx.x;
    const int lane = tid & 63, wave = tid >> 6;
    const int bm = blockIdx.y * 128, bn = blockIdx.x * 64;
    const int wm = wave * 32;
    const int row16 = lane & 15, quad = lane >> 4;
    const int srow = lane >> 3;
    const int sc16 = (lane & 7) ^ srow;
    const unsigned short* gA = A + (size_t)(bm + wave * 32 + srow) * K + sc16 * 8;
    const unsigned short* gB = B + (size_t)(bn + wave * 16 + srow) * K + sc16 * 8;
    unsigned short* lA = sA + (wave * 4) * 512;
    unsigned short* lB = sB + (wave * 2) * 512;
    fx4 acc[2][4] = {};

    for (int kt = 0; kt < K; kt += 64) {
#pragma unroll
        for (int it = 0; it < 4; ++it)
            gl2lds16(gA + (size_t)it * 8 * K + kt, lA + it * 512);
#pragma unroll
        for (int it = 0; it < 2; ++it)
            gl2lds16(gB + (size_t)it * 8 * K + kt, lB + it * 512);
        __syncthreads();
#pragma unroll
        for (int kk = 0; kk < 64; kk += 32) {
            FragU af[2], bf[4];
#pragma unroll
            for (int t = 0; t < 2; ++t) {
                int ra = wm + t * 16 + row16;
                af[t].i = *(const ix4*)(sA + ra * 64 + ((quad + (kk >> 3)) ^ (ra & 7)) * 8);
            }
#pragma unroll
            for (int t = 0; t < 4; ++t) {
                int rb = t * 16 + row16;
                bf[t].i = *(const ix4*)(sB + rb * 64 + ((quad + (kk >> 3)) ^ (rb & 7)) * 8);
            }
#pragma unroll
            for (int tm = 0; tm < 2; ++tm)
#pragma unroll
                for (int tn = 0; tn < 4; ++tn)
                    acc[tm][tn] = __builtin_amdgcn_mfma_f32_16x16x32_bf16(
                        af[tm].b, bf[tn].b, acc[tm][tn], 0, 0, 0);
        }
        __syncthreads();
    }
#pragma unroll
    for (int tm = 0; tm < 2; ++tm) {
        int row0 = bm + wm + tm * 16 + quad * 4;
#pragma unroll
        for (int tn = 0; tn < 4; ++tn) {
            int col = bn + tn * 16 + row16;
#pragma unroll
            for (int r = 0; r < 4; ++r)
                C[(size_t)(row0 + r) * N + col] = acc[tm][tn][r];
        }
    }
}

// ---------- fused middle: conv+silu -> LDS xc -> xproj MFMA -> delta/G -> SSM -> y2 ----------
// grid 256 blocks x 256 thr; block owns 16 rows. xc never touches global memory.
// LDS xc layout: row-major 16x2048 bf16 with 16B-col XOR swizzle (phys c16 = c16 ^ (row&7)).
__global__ __launch_bounds__(256) void fused_mid_k(const unsigned short* __restrict__ xz,
                                                   const float* __restrict__ cw,
                                                   const unsigned short* __restrict__ wxb,
                                                   const float* __restrict__ Alog,
                                                   const float* __restrict__ Dv,
                                                   unsigned short* __restrict__ y2) {
    __shared__ __align__(16) unsigned short sxc[16 * 2048];   // 64 KB
    __shared__ float sX[4][16][49];
    __shared__ float sdg[16 * 17];
    const int tid  = threadIdx.x;
    const int lane = tid & 63, wave = tid >> 6;
    const int row16 = lane & 15, quad = lane >> 4;
    const int m0 = blockIdx.x * 16;

    // ---- phase 1: conv(K=4, causal) + silu for 16 rows x 2048 ch ----
    {
        const float4* cw4 = (const float4*)cw;
        float w[8][4];
#pragma unroll
        for (int c = 0; c < 8; ++c) {
            float4 t4 = cw4[tid * 8 + c];
            w[c][0] = t4.x; w[c][1] = t4.y; w[c][2] = t4.z; w[c][3] = t4.w;
        }
        for (int j = 0; j < 16; ++j) {
            const int m = m0 + j, s = m & 2047;
            float acc[8] = {0, 0, 0, 0, 0, 0, 0, 0};
#pragma unroll
            for (int k = 0; k < 4; ++k) {
                if (s - 3 + k >= 0) {          // row-uniform branch
                    const unsigned short* p = xz + (size_t)(m - 3 + k) * 4096 + tid * 8;
                    ushort4 a = *(const ushort4*)p;
                    ushort4 b = *(const ushort4*)(p + 4);
                    float v[8] = {b2f(a.x), b2f(a.y), b2f(a.z), b2f(a.w),
                                  b2f(b.x), b2f(b.y), b2f(b.z), b2f(b.w)};
#pragma unroll
                    for (int c = 0; c < 8; ++c) acc[c] += v[c] * w[c][k];
                }
            }
            unsigned short* q = sxc + j * 2048 + ((tid ^ (j & 7)) * 8);
            *(ushort4*)q       = make_ushort4(f2b(silu_f(acc[0])), f2b(silu_f(acc[1])),
                                              f2b(silu_f(acc[2])), f2b(silu_f(acc[3])));
            *(ushort4*)(q + 4) = make_ushort4(f2b(silu_f(acc[4])), f2b(silu_f(acc[5])),
                                              f2b(silu_f(acc[6])), f2b(silu_f(acc[7])));
        }
    }
    __syncthreads();

    // ---- phase 2: xproj = xc @ Wx^T (N=33 pad 48); wave = K-quarter; A from LDS ----
    {
        fx4 acc[3] = {};
        const unsigned short* bp = wxb + (size_t)row16 * 2048 + wave * 512 + quad * 8;
        const int cbase = wave * 64 + quad;
#pragma unroll 4
        for (int kk = 0; kk < 512; kk += 32) {
            FragU a, b0, b1, b2;
            int c16 = cbase + (kk >> 3);
            a.i  = *(const ix4*)(sxc + row16 * 2048 + ((c16 ^ (row16 & 7)) * 8));
            b0.i = *(const ix4*)(bp + kk);
            b1.i = *(const ix4*)(bp + 16 * 2048 + kk);
            b2.i = *(const ix4*)(bp + 32 * 2048 + kk);
            acc[0] = __builtin_amdgcn_mfma_f32_16x16x32_bf16(a.b, b0.b, acc[0], 0, 0, 0);
            acc[1] = __builtin_amdgcn_mfma_f32_16x16x32_bf16(a.b, b1.b, acc[1], 0, 0, 0);
            acc[2] = __builtin_amdgcn_mfma_f32_16x16x32_bf16(a.b, b2.b, acc[2], 0, 0, 0);
        }
#pragma unroll
        for (int t = 0; t < 3; ++t)
#pragma unroll
            for (int r = 0; r < 4; ++r)
                sX[wave][quad * 4 + r][t * 16 + row16] = acc[t][r];
    }
    __syncthreads();
    for (int idx = tid; idx < 272; idx += 256) {
        int rr = idx / 17, q = idx - rr * 17;
        float o;
        if (q == 0) {
            float v = sX[0][rr][0] + sX[1][rr][0] + sX[2][rr][0] + sX[3][rr][0];
            o = (v > 20.f) ? v : log1pf(fexp(v));          // softplus(delta_raw)
        } else {
            float bs = sX[0][rr][q]      + sX[1][rr][q]      + sX[2][rr][q]      + sX[3][rr][q];
            float cs = sX[0][rr][q + 16] + sX[1][rr][q + 16] + sX[2][rr][q + 16] + sX[3][rr][q + 16];
            o = bs * cs;                                   // G[n] = B[n]*C[n]
        }
        sdg[rr * 17 + q] = o;
    }
    __syncthreads();

    // ---- phase 3: SSM pointwise; 2 passes x 4 channels/thread, A_log in regs ----
#pragma unroll 1
    for (int p = 0; p < 2; ++p) {
        const int ch0 = p * 1024 + tid * 4;
        float a2[4][16];
#pragma unroll
        for (int c = 0; c < 4; ++c) {
            const float4* ar = (const float4*)(Alog + (size_t)(ch0 + c) * 16);
#pragma unroll
            for (int n4 = 0; n4 < 4; ++n4) {
                float4 t4 = ar[n4];
                a2[c][n4 * 4 + 0] = -fexp(t4.x) * LOG2E;
                a2[c][n4 * 4 + 1] = -fexp(t4.y) * LOG2E;
                a2[c][n4 * 4 + 2] = -fexp(t4.z) * LOG2E;
                a2[c][n4 * 4 + 3] = -fexp(t4.w) * LOG2E;
            }
        }
        float4 dvv = *(const float4*)(Dv + ch0);
        float dv[4] = {dvv.x, dvv.y, dvv.z, dvv.w};
        const int c16 = ch0 >> 3, sub = ch0 & 7;
        for (int j = 0; j < 16; ++j) {
            const int m = m0 + j;
            float delta = sdg[j * 17];
            float Gr[16];
#pragma unroll
            for (int n = 0; n < 16; ++n) Gr[n] = sdg[j * 17 + 1 + n];
            ushort4 xu = *(const ushort4*)(sxc + j * 2048 + ((c16 ^ (j & 7)) * 8) + sub);
            ushort4 zu = *(const ushort4*)(xz + (size_t)m * 4096 + 2048 + ch0);
            float xcv[4] = {b2f(xu.x), b2f(xu.y), b2f(xu.z), b2f(xu.w)};
            float zv[4]  = {b2f(zu.x), b2f(zu.y), b2f(zu.z), b2f(zu.w)};
            unsigned short ov[4];
#pragma unroll
            for (int c = 0; c < 4; ++c) {
                float ssum = 0.f;
#pragma unroll
                for (int n = 0; n < 16; ++n)
                    ssum += Gr[n] * __builtin_amdgcn_exp2f(delta * a2[c][n]);
                float y = xcv[c] * (dv[c] + ssum);
                ov[c] = f2b(y * silu_f(zv[c]));
            }
            *(ushort4*)(y2 + (size_t)m * 2048 + ch0) = make_ushort4(ov[0], ov[1], ov[2], ov[3]);
        }
    }
}

// ---------- launch ----------
extern "C" void kernel_launch(void* const* d_in, const int* in_sizes, int n_in,
                              void* d_out, int out_size, void* d_ws, size_t ws_size,
                              hipStream_t stream) {
    const float* x      = (const float*)d_in[0];   // (2,2048,1024)
    const float* W_in   = (const float*)d_in[1];   // (4096,1024)
    const float* conv_w = (const float*)d_in[2];   // (2048,1,4)
    const float* W_x    = (const float*)d_in[3];   // (33,2048)
    const float* A_log  = (const float*)d_in[4];   // (2048,16)
    const float* Dvec   = (const float*)d_in[5];   // (2048,)
    const float* W_out  = (const float*)d_in[6];   // (1024,2048)

    char* ws = (char*)d_ws;
    unsigned short* xb  = (unsigned short*)(ws);              //  8,388,608  x bf16
    unsigned short* wib = (unsigned short*)(ws + 8388608);    //  8,388,608  W_in bf16
    unsigned short* wob = (unsigned short*)(ws + 16777216);   //  4,194,304  W_out bf16
    unsigned short* xz  = (unsigned short*)(ws + 20971520);   // 33,554,432  xz bf16 (4096x4096)
    unsigned short* y2  = (unsigned short*)(ws + 54525952);   // 16,777,216  y2 bf16 (4096x2048)
    unsigned short* wxb = (unsigned short*)(ws + 71303168);   //    196,608  Wx bf16 (48x2048 padded)

    cvt_all_k<<<10306, 256, 0, stream>>>(x, W_in, W_out, W_x, xb, wib, wob, wxb);
    // xz[m,i] = sum_h x[m,h] * W_in[i,h]
    gemm_bt<true><<<dim3(32, 32), 256, 0, stream>>>(xb, wib, xz, 4096, 1024);
    // conv+silu -> xproj -> delta/G -> SSM gate, all in one dispatch
    fused_mid_k<<<256, 256, 0, stream>>>(xz, conv_w, wxb, A_log, Dvec, y2);
    // out[m,h] = sum_i y2[m,i] * W_out[h,i]
    gemm_bt_n64<<<dim3(16, 32), 256, 0, stream>>>(y2, wob, (float*)d_out, 1024, 2048);
}